// Round 5
// baseline (238.069 us; speedup 1.0000x reference)
//
#include <hip/hip_runtime.h>
#include <hip/hip_cooperative_groups.h>

namespace cg = cooperative_groups;

#define N_NODES   100000
#define N_EDGES   600000
#define D_FEAT    128
#define N_CLASSES 64
#define N_TILES   (N_NODES / 16)     // 6250, exact
#define GRID_BLKS 512                // 2 blocks/CU needed — large co-residency margin

typedef short bf16x8 __attribute__((ext_vector_type(8)));
typedef float f32x4  __attribute__((ext_vector_type(4)));
typedef unsigned short u16x8 __attribute__((ext_vector_type(8)));
typedef unsigned short u16x4 __attribute__((ext_vector_type(4)));  // NT-storable

__device__ __forceinline__ unsigned short f2bf(float f) {
    unsigned int u = __float_as_uint(f);
    unsigned int r = (u + 0x7fffu + ((u >> 16) & 1u)) >> 16;   // RNE
    return (unsigned short)r;
}
__device__ __forceinline__ float bf2f(unsigned short u) {
    return __uint_as_float((unsigned int)u << 16);
}

// ---------------------------------------------------------------------------
// Shared device pieces.
// Wc LDS layout: 128 rows x 128 bf16, 16B-chunk XOR swizzle (chunk ^= row&15)
// so the MFMA A-frag ds_read_b128 across 16 rows is 2-way (free) not 16-way.
// ---------------------------------------------------------------------------
__device__ __forceinline__ void build_wc_lds(unsigned short* WcS,
                                             const float* __restrict__ W,
                                             int t) {
#pragma unroll
    for (int i = 0; i < 16; ++i) {
        int cc = i * 256 + t;                   // 0..4095 (4-elem chunks)
        int c  = cc >> 5;                       // row 0..127
        int kc = (cc & 31) << 2;                // ushort offset 0,4,...,124
        const float* wp = (c < 64) ? (W + c * 256 + kc)
                                   : (W + (c - 64) * 256 + 128 + kc);
        f32x4 v = *(const f32x4*)wp;
        u16x4 pk;
        pk[0] = f2bf(v[0]); pk[1] = f2bf(v[1]);
        pk[2] = f2bf(v[2]); pk[3] = f2bf(v[3]);
        int phys = (((kc >> 3) ^ (c & 15)) << 3) | (kc & 7);  // 16B-chunk XOR swizzle
        *(u16x4*)(WcS + c * 128 + phys) = pk;
    }
}

// One 16-node tile: MFMA proj + bias + NT bf16 store to P.
// A frag: ch = ct*16 + m, k = quad*8+j (LDS, swizzled)
// B frag: node = n0 + m,  k = quad*8+j (h, NT loads)
// D: row=channel = ct*16 + quad*4 + r, col=node = n0 + m
__device__ __forceinline__ void proj_tile(const unsigned short* WcS,
                                          const float* __restrict__ h,
                                          const f32x4* bias,   // [4], for ct<4
                                          unsigned short* __restrict__ P,
                                          int n0, int m, int quad) {
    bf16x8 hfrag[4];
    const float* hrow = h + (size_t)(n0 + m) * 128 + quad * 8;
#pragma unroll
    for (int ks = 0; ks < 4; ++ks) {
        f32x4 v0 = __builtin_nontemporal_load((const f32x4*)(hrow + ks * 32));
        f32x4 v1 = __builtin_nontemporal_load((const f32x4*)(hrow + ks * 32 + 4));
        bf16x8 a;
        a[0] = (short)f2bf(v0[0]); a[1] = (short)f2bf(v0[1]);
        a[2] = (short)f2bf(v0[2]); a[3] = (short)f2bf(v0[3]);
        a[4] = (short)f2bf(v1[0]); a[5] = (short)f2bf(v1[1]);
        a[6] = (short)f2bf(v1[2]); a[7] = (short)f2bf(v1[3]);
        hfrag[ks] = a;
    }

    f32x4 acc[8];
#pragma unroll
    for (int ct = 0; ct < 8; ++ct) acc[ct] = (f32x4){0.f, 0.f, 0.f, 0.f};

#pragma unroll
    for (int ct = 0; ct < 8; ++ct) {
        const unsigned short* wbase = WcS + (ct * 16 + m) * 128;
#pragma unroll
        for (int ks = 0; ks < 4; ++ks) {
            // logical chunk = ks*4+quad, row&15 = m -> phys chunk = chunk^m
            bf16x8 wfrag = *(const bf16x8*)(wbase + (((ks * 4 + quad) ^ m) << 3));
            acc[ct] = __builtin_amdgcn_mfma_f32_16x16x32_bf16(wfrag, hfrag[ks], acc[ct], 0, 0, 0);
        }
    }

    unsigned short* prow = P + (size_t)(n0 + m) * 128;
#pragma unroll
    for (int ct = 0; ct < 8; ++ct) {
        const int cb = ct * 16 + quad * 4;      // channel base, multiple of 4
        float v[4];
        if (ct < 4) {                           // bias folded into Wu half
#pragma unroll
            for (int r = 0; r < 4; ++r) v[r] = acc[ct][r] + bias[ct][r];
        } else {
#pragma unroll
            for (int r = 0; r < 4; ++r) v[r] = acc[ct][r];
        }
        u16x4 pk;
        pk[0] = f2bf(v[0]); pk[1] = f2bf(v[1]);
        pk[2] = f2bf(v[2]); pk[3] = f2bf(v[3]);
        __builtin_nontemporal_store(pk, (u16x4*)(prow + cb));
    }
}

// Two edges (e0, e0+300000) for one lane: 4x 16B gathers, 4x NT f32x4 stores.
__device__ __forceinline__ void edge_item(int g,
                                          const int* __restrict__ src,
                                          const int* __restrict__ dst,
                                          const unsigned short* __restrict__ P,
                                          float* __restrict__ out) {
    int e0 = g >> 3;
    int c0 = (g & 7) << 3;                      // 0,8,...,56
    int e1 = e0 + (N_EDGES / 2);
    int s0 = src[e0], d0 = dst[e0];
    int s1 = src[e1], d1 = dst[e1];
    u16x8 us0 = *(const u16x8*)(P + (size_t)s0 * 128 + c0);
    u16x8 ud0 = *(const u16x8*)(P + (size_t)d0 * 128 + 64 + c0);
    u16x8 us1 = *(const u16x8*)(P + (size_t)s1 * 128 + c0);
    u16x8 ud1 = *(const u16x8*)(P + (size_t)d1 * 128 + 64 + c0);

    f32x4 a0, a1, b0, b1;
#pragma unroll
    for (int j = 0; j < 4; ++j) {
        a0[j] = bf2f(us0[j])     + bf2f(ud0[j]);
        a1[j] = bf2f(us0[j + 4]) + bf2f(ud0[j + 4]);
        b0[j] = bf2f(us1[j])     + bf2f(ud1[j]);
        b1[j] = bf2f(us1[j + 4]) + bf2f(ud1[j + 4]);
    }
    float* op0 = out + (size_t)e0 * 64 + c0;
    float* op1 = out + (size_t)e1 * 64 + c0;
    __builtin_nontemporal_store(a0, (f32x4*)op0);
    __builtin_nontemporal_store(a1, (f32x4*)(op0 + 4));
    __builtin_nontemporal_store(b0, (f32x4*)op1);
    __builtin_nontemporal_store(b1, (f32x4*)(op1 + 4));
}

// ---------------------------------------------------------------------------
// Fused persistent cooperative kernel (phase1 proj -> grid sync -> phase2 edge)
// ---------------------------------------------------------------------------
__global__ __launch_bounds__(256, 2) void fused_kernel(
        const float* __restrict__ h,
        const float* __restrict__ W,
        const float* __restrict__ b,
        unsigned short* __restrict__ P,
        const int* __restrict__ src,
        const int* __restrict__ dst,
        float* __restrict__ out) {
    __shared__ unsigned short WcS[128 * 128];   // 32 KiB

    const int t    = threadIdx.x;
    const int lane = t & 63;
    const int wid  = t >> 6;
    const int m    = lane & 15;
    const int quad = lane >> 4;

    build_wc_lds(WcS, W, t);
    __syncthreads();

    f32x4 bias[4];
#pragma unroll
    for (int ct = 0; ct < 4; ++ct)
        bias[ct] = *(const f32x4*)(b + ct * 16 + quad * 4);

    for (int tile = blockIdx.x * 4 + wid; tile < N_TILES; tile += gridDim.x * 4)
        proj_tile(WcS, h, bias, P, tile * 16, m, quad);

    // Device-scope visibility across non-coherent XCD L2s, then grid barrier.
    __threadfence();
    cg::this_grid().sync();

    const int total  = (N_EDGES / 2) * 8;       // 2.4M work items
    const int stride = gridDim.x * 256;
    for (int g = blockIdx.x * 256 + t; g < total; g += stride)
        edge_item(g, src, dst, P, out);
}

// ---------------------------------------------------------------------------
// Fallback path A (verified R2 structure): two kernels, stream-ordered.
// ---------------------------------------------------------------------------
__global__ __launch_bounds__(256) void proj_mfma(const float* __restrict__ h,
                                                 const float* __restrict__ W,
                                                 const float* __restrict__ b,
                                                 unsigned short* __restrict__ P) {
    __shared__ unsigned short WcS[128 * 128];
    const int t    = threadIdx.x;
    const int lane = t & 63;
    const int wid  = t >> 6;
    const int m    = lane & 15;
    const int quad = lane >> 4;

    build_wc_lds(WcS, W, t);
    __syncthreads();

    const int tile = blockIdx.x * 4 + wid;
    if (tile >= N_TILES) return;

    f32x4 bias[4];
#pragma unroll
    for (int ct = 0; ct < 4; ++ct)
        bias[ct] = *(const f32x4*)(b + ct * 16 + quad * 4);

    proj_tile(WcS, h, bias, P, tile * 16, m, quad);
}

__global__ __launch_bounds__(256) void edge_kernel(const int* __restrict__ src,
                                                   const int* __restrict__ dst,
                                                   const unsigned short* __restrict__ P,
                                                   float* __restrict__ out) {
    int g = blockIdx.x * 256 + threadIdx.x;     // exact grid: 300000*8
    edge_item(g, src, dst, P, out);
}

// ---------------------------------------------------------------------------
// Fallback path B (ws too small): direct per-edge fp32 dot products.
// ---------------------------------------------------------------------------
__global__ __launch_bounds__(256) void direct_kernel(const float* __restrict__ h,
                                                     const int* __restrict__ src,
                                                     const int* __restrict__ dst,
                                                     const float* __restrict__ W,
                                                     const float* __restrict__ b,
                                                     float* __restrict__ out) {
    __shared__ float hcat[4][256];
    int t = threadIdx.x;
    int w = t >> 6, lane = t & 63;
    int e = blockIdx.x * 4 + w;
    bool valid = (e < N_EDGES);
    if (valid) {
        int s = src[e], d = dst[e];
        const float* p = (lane < 32) ? (h + (size_t)s * 128 + lane * 4)
                                     : (h + (size_t)d * 128 + (lane - 32) * 4);
        *(float4*)&hcat[w][lane * 4] = *(const float4*)p;
    }
    __syncthreads();
    if (!valid) return;
    int c = lane;
    float acc = 0.f;
    for (int k = 0; k < 256; k += 4) {
        float4 wv = *(const float4*)(W + c * 256 + k);
        acc += hcat[w][k] * wv.x + hcat[w][k + 1] * wv.y
             + hcat[w][k + 2] * wv.z + hcat[w][k + 3] * wv.w;
    }
    out[(size_t)e * 64 + c] = acc + b[c];
}

extern "C" void kernel_launch(void* const* d_in, const int* in_sizes, int n_in,
                              void* d_out, int out_size, void* d_ws, size_t ws_size,
                              hipStream_t stream) {
    const float* h   = (const float*)d_in[0];
    const int*   src = (const int*)d_in[1];
    const int*   dst = (const int*)d_in[2];
    const float* W   = (const float*)d_in[3];
    const float* b   = (const float*)d_in[4];
    float* out = (float*)d_out;

    const size_t p_bytes = (size_t)N_NODES * 128 * sizeof(unsigned short);   // 25.6 MB
    if (ws_size >= p_bytes) {
        unsigned short* P = (unsigned short*)d_ws;
        static int coop_ok = -1;                 // -1 unknown, 0 no, 1 yes
        bool launched = false;
        if (coop_ok != 0) {
            void* args[] = {(void*)&h, (void*)&W, (void*)&b, (void*)&P,
                            (void*)&src, (void*)&dst, (void*)&out};
            hipError_t e = hipLaunchCooperativeKernel((const void*)fused_kernel,
                                                      dim3(GRID_BLKS), dim3(256),
                                                      args, 0, stream);
            if (e == hipSuccess) { coop_ok = 1; launched = true; }
            else                 { coop_ok = 0; }
        }
        if (!launched) {
            const int n_blocks = (N_TILES + 3) / 4;                          // 1563
            proj_mfma<<<n_blocks, 256, 0, stream>>>(h, W, b, P);
            edge_kernel<<<(N_EDGES / 2 * 8) / 256, 256, 0, stream>>>(src, dst, P, out);
        }
    } else {
        direct_kernel<<<(N_EDGES + 3) / 4, 256, 0, stream>>>(h, src, dst, W, b, out);
    }
}